// Round 15
// baseline (135.899 us; speedup 1.0000x reference)
//
#include <hip/hip_runtime.h>
#include <hip/hip_cooperative_groups.h>
#include <math.h>

namespace cg = cooperative_groups;

static constexpr int B_ = 32, M_ = 100, L_ = 30, LQ_ = 30, E_ = 256, V_ = 32000;

typedef __attribute__((ext_vector_type(8))) short bf16x8;
typedef __attribute__((ext_vector_type(4))) float f32x4;

__device__ __forceinline__ unsigned f2bf(float f) {   // RNE f32 -> bf16 bits
    unsigned u = __float_as_uint(f);
    return (u + 0x7FFFu + ((u >> 16) & 1u)) >> 16;
}

// ---------------- Kernel 1: story embeddings (fused 4 tables; ~66us line-fill wall).
__global__ __launch_bounds__(256) void k_embed(const int* __restrict__ trainS,
                                               const float* __restrict__ A1,
                                               const float* __restrict__ A2,
                                               const float* __restrict__ A3,
                                               const float* __restrict__ A4,
                                               float* __restrict__ embA) {
    const int bm = blockIdx.x;
    const int tbl = threadIdx.x >> 6;
    const int e0 = (threadIdx.x & 63) * 4;
    const float* __restrict__ A = (tbl == 0) ? A1 : (tbl == 1) ? A2 : (tbl == 2) ? A3 : A4;
    const float half_e = (E_ + 1) * 0.5f;
    const float half_j = (L_ + 1) * 0.5f;
    const float inv = 1.0f / (float)(E_ * L_);
    const float k0 = (float)(e0 + 1) - half_e;
    const float k1 = k0 + 1.f, k2 = k0 + 2.f, k3 = k0 + 3.f;

    int idx[L_];
#pragma unroll
    for (int l = 0; l < L_; ++l) idx[l] = trainS[bm * L_ + l];

    float4 acc = make_float4(0.f, 0.f, 0.f, 0.f);
#pragma unroll
    for (int c = 0; c < 2; ++c) {
        float4 r[15];
#pragma unroll
        for (int j = 0; j < 15; ++j)
            r[j] = *reinterpret_cast<const float4*>(A + (size_t)idx[c * 15 + j] * E_ + e0);
        __builtin_amdgcn_sched_barrier(0);
#pragma unroll
        for (int j = 0; j < 15; ++j) {
            const int l = c * 15 + j;
            const float coef = 4.0f * ((float)(l + 1) - half_j) * inv;
            acc.x += r[j].x * (1.0f + coef * k0);
            acc.y += r[j].y * (1.0f + coef * k1);
            acc.z += r[j].z * (1.0f + coef * k2);
            acc.w += r[j].w * (1.0f + coef * k3);
        }
    }
    *reinterpret_cast<float4*>(embA + (size_t)tbl * (B_ * M_ * E_) + (size_t)bm * E_ + e0) = acc;
}

// ---------------- Kernel 2: query embedding + three hops (R13 latency-restructured).
__global__ __launch_bounds__(1024) void k_hops(const int* __restrict__ trainQ,
                                               const float* __restrict__ trainQM,
                                               const float* __restrict__ A1,
                                               const float* __restrict__ embA,
                                               const float* __restrict__ trainPM,
                                               float* __restrict__ u_N,
                                               float* __restrict__ partial) {
    const int b = blockIdx.x;
    const int tid = threadIdx.x;
    const int lane = tid & 63;
    const int wave = tid >> 6;
    const int g = tid >> 8;
    const int e = tid & 255;
    if (tid < 8) partial[b * 8 + tid] = 0.f;
    __shared__ float u_sh[E_];
    __shared__ float sc[M_];
    __shared__ float p_sh[M_];
    __shared__ float osum[4][E_];

    {   // query embedding
        const float half_e = (E_ + 1) * 0.5f;
        const float half_j = (LQ_ + 1) * 0.5f;
        const float inv = 1.0f / (float)(E_ * LQ_);
        const float ke = (float)(e + 1) - half_e;
        const int l0 = g * 8;
        const int ln = (LQ_ - l0 < 8) ? (LQ_ - l0) : 8;
        int qi[8];
        float qm[8];
#pragma unroll
        for (int j = 0; j < 8; ++j) {
            if (j < ln) {
                qi[j] = trainQ[b * LQ_ + l0 + j];
                qm[j] = trainQM[b * LQ_ + l0 + j];
            } else { qi[j] = 0; qm[j] = 0.f; }
        }
        float r[8];
#pragma unroll
        for (int j = 0; j < 8; ++j)
            r[j] = (j < ln) ? A1[(size_t)qi[j] * E_ + e] : 0.f;
        float part = 0.f;
#pragma unroll
        for (int j = 0; j < 8; ++j) {
            const float pe = 1.0f + 4.0f * ke * ((float)(l0 + j + 1) - half_j) * inv;
            part += r[j] * pe * qm[j];
        }
        osum[g][e] = part;
    }
    __syncthreads();
    if (tid < E_) u_sh[tid] = osum[0][tid] + osum[1][tid] + osum[2][tid] + osum[3][tid];
    __syncthreads();

    for (int hop = 0; hop < 3; ++hop) {
        const float* memA = embA + (size_t)hop * (B_ * M_ * E_) + (size_t)b * M_ * E_;
        const float* memC = memA + (size_t)(B_ * M_ * E_);

        float rv[7][4];
#pragma unroll
        for (int t = 0; t < 7; ++t) {
            const int m = wave + t * 16;
            if (m < M_) {
                const float* row = memA + (size_t)m * E_;
#pragma unroll
                for (int j = 0; j < 4; ++j) rv[t][j] = row[lane + 64 * j];
            }
        }
        __builtin_amdgcn_sched_barrier(0);
#pragma unroll
        for (int t = 0; t < 7; ++t) {
            const int m = wave + t * 16;
            if (m < M_) {
                float part = rv[t][0] * u_sh[lane] + rv[t][1] * u_sh[lane + 64]
                           + rv[t][2] * u_sh[lane + 128] + rv[t][3] * u_sh[lane + 192];
#pragma unroll
                for (int off = 32; off > 0; off >>= 1)
                    part += __shfl_xor(part, off, 64);
                if (lane == 0) sc[m] = part * trainPM[b * M_ + m];
            }
        }

        float cv[25];
        {
            const float* crow = memC + e;
            const int m0 = g * 25;
#pragma unroll
            for (int mm = 0; mm < 25; ++mm)
                cv[mm] = crow[(size_t)(m0 + mm) * E_];
        }
        __builtin_amdgcn_sched_barrier(0);
        __syncthreads();

        if (wave == 0) {
            const float pm0 = (lane < M_) ? trainPM[b * M_ + lane] : 0.f;
            const float pm1 = (lane + 64 < M_) ? trainPM[b * M_ + lane + 64] : 0.f;
            const float x0 = (lane < M_ && pm0 > 0.f) ? sc[lane] : -1e30f;
            const float x1 = (lane + 64 < M_ && pm1 > 0.f) ? sc[lane + 64] : -1e30f;
            float mx = fmaxf(x0, x1);
#pragma unroll
            for (int off = 32; off > 0; off >>= 1)
                mx = fmaxf(mx, __shfl_xor(mx, off, 64));
            const float e0v = (lane < M_) ? expf(x0 - mx) * pm0 : 0.f;
            const float e1v = (lane + 64 < M_) ? expf(x1 - mx) * pm1 : 0.f;
            float ssum = e0v + e1v;
#pragma unroll
            for (int off = 32; off > 0; off >>= 1)
                ssum += __shfl_xor(ssum, off, 64);
            const float invs = 1.0f / (ssum + 1e-13f);
            if (lane < M_) p_sh[lane] = e0v * invs;
            if (lane + 64 < M_) p_sh[lane + 64] = e1v * invs;
        }
        __syncthreads();

        {
            float acc = 0.f;
            const int m0 = g * 25;
#pragma unroll
            for (int mm = 0; mm < 25; ++mm)
                acc += p_sh[m0 + mm] * cv[mm];
            osum[g][e] = acc;
        }
        __syncthreads();
        if (tid < E_) u_sh[tid] += osum[0][tid] + osum[1][tid] + osum[2][tid] + osum[3][tid];
        __syncthreads();
    }
    if (tid < E_) u_N[b * E_ + tid] = u_sh[tid];
}

// ---------------- Kernel 3 (COOPERATIVE): MFMA GEMM + batch-LN + exp-partials + grid.sync
// + LSE subtract + final write. z kept in registers; no z buffer, no k_final.
__global__ __launch_bounds__(256) void k_output(const float* __restrict__ u_N,
                                                const float* __restrict__ Wm,
                                                const float* __restrict__ gamma,
                                                const float* __restrict__ beta,
                                                const float* __restrict__ VM,
                                                float* __restrict__ out,
                                                float* __restrict__ partial) {
    __shared__ char uAraw[32 * 512];   // bf16 u[m][k], swizzled 16B granules
    __shared__ float pex[B_];
    __shared__ float lse_sh[B_];
    const int tid = threadIdx.x;
    {
        const int m = tid >> 3;
        const int kc = (tid & 7) * 32;
        const float4* src = reinterpret_cast<const float4*>(u_N + m * E_ + kc);
#pragma unroll
        for (int j = 0; j < 4; ++j) {
            const float4 f0 = src[2 * j];
            const float4 f1 = src[2 * j + 1];
            uint4 q;
            q.x = f2bf(f0.x) | (f2bf(f0.y) << 16);
            q.y = f2bf(f0.z) | (f2bf(f0.w) << 16);
            q.z = f2bf(f1.x) | (f2bf(f1.y) << 16);
            q.w = f2bf(f1.z) | (f2bf(f1.w) << 16);
            const int k16 = kc / 8 + j;
            const int off = m * 512 + ((k16 * 16) ^ ((m & 7) << 4));
            *reinterpret_cast<uint4*>(uAraw + off) = q;
        }
    }
    if (tid < B_) pex[tid] = 0.f;
    __syncthreads();

    const int lane = tid & 63;
    const int wv = tid >> 6;
    const int col = lane & 15;
    const int grp = lane >> 4;
    const int n0 = (blockIdx.x * 4 + wv) * 16;
    const int v = n0 + col;

    float4 wreg[16];
    {
        const float* wrow = Wm + (size_t)v * E_ + grp * 8;
#pragma unroll
        for (int s = 0; s < 8; ++s) {
            wreg[2 * s] = *reinterpret_cast<const float4*>(wrow + s * 32);
            wreg[2 * s + 1] = *reinterpret_cast<const float4*>(wrow + s * 32 + 4);
        }
    }
    __builtin_amdgcn_sched_barrier(0);

    bf16x8 af[2][8];
#pragma unroll
    for (int mt = 0; mt < 2; ++mt) {
        const int m = mt * 16 + col;
#pragma unroll
        for (int s = 0; s < 8; ++s) {
            const int k16 = s * 4 + grp;
            const int off = m * 512 + ((k16 * 16) ^ ((m & 7) << 4));
            af[mt][s] = *reinterpret_cast<bf16x8*>(uAraw + off);
        }
    }

    f32x4 acc0 = {0.f, 0.f, 0.f, 0.f};
    f32x4 acc1 = {0.f, 0.f, 0.f, 0.f};
#pragma unroll
    for (int s = 0; s < 8; ++s) {
        const float4 w0 = wreg[2 * s], w1 = wreg[2 * s + 1];
        bf16x8 bf;
        bf[0] = (short)f2bf(w0.x); bf[1] = (short)f2bf(w0.y);
        bf[2] = (short)f2bf(w0.z); bf[3] = (short)f2bf(w0.w);
        bf[4] = (short)f2bf(w1.x); bf[5] = (short)f2bf(w1.y);
        bf[6] = (short)f2bf(w1.z); bf[7] = (short)f2bf(w1.w);
        acc0 = __builtin_amdgcn_mfma_f32_16x16x32_bf16(af[0][s], bf, acc0, 0, 0, 0);
        acc1 = __builtin_amdgcn_mfma_f32_16x16x32_bf16(af[1][s], bf, acc1, 0, 0, 0);
    }

    float s1 = 0.f, s2 = 0.f;
#pragma unroll
    for (int r = 0; r < 4; ++r) {
        s1 += acc0[r] + acc1[r];
        s2 += acc0[r] * acc0[r] + acc1[r] * acc1[r];
    }
    s1 += __shfl_xor(s1, 16, 64);
    s2 += __shfl_xor(s2, 16, 64);
    s1 += __shfl_xor(s1, 32, 64);
    s2 += __shfl_xor(s2, 32, 64);
    const float mean = s1 * (1.0f / B_);
    const float var = s2 * (1.0f / B_) - mean * mean;
    const float rstd = rsqrtf(var + 1e-5f);
    const float gg = gamma[v], be = beta[v];

    // z values kept in registers; exp partials shfl-reduced across the 16 cols.
    float zr[2][4], ex[2][4];
#pragma unroll
    for (int mt = 0; mt < 2; ++mt) {
#pragma unroll
        for (int r = 0; r < 4; ++r) {
            const int b = mt * 16 + grp * 4 + r;
            const float wx = (mt == 0) ? acc0[r] : acc1[r];
            const float y = gg * (wx - mean) * rstd + be;
            const float vm = VM[(size_t)b * V_ + v] + 1e-13f;
            zr[mt][r] = y + logf(vm);
            ex[mt][r] = vm * expf(y);
        }
    }
#pragma unroll
    for (int off = 1; off < 16; off <<= 1) {
#pragma unroll
        for (int mt = 0; mt < 2; ++mt)
#pragma unroll
            for (int r = 0; r < 4; ++r)
                ex[mt][r] += __shfl_xor(ex[mt][r], off, 64);
    }
    if (col == 0) {
#pragma unroll
        for (int mt = 0; mt < 2; ++mt)
#pragma unroll
            for (int r = 0; r < 4; ++r)
                atomicAdd(&pex[mt * 16 + grp * 4 + r], ex[mt][r]);
    }
    __syncthreads();
    if (tid < B_) atomicAdd(&partial[tid * 8 + (blockIdx.x & 7)], pex[tid]);

    cg::this_grid().sync();

    if (tid < B_) {
        float s = 0.f;
#pragma unroll
        for (int k = 0; k < 8; ++k) s += partial[tid * 8 + k];
        lse_sh[tid] = logf(s);
    }
    __syncthreads();

#pragma unroll
    for (int mt = 0; mt < 2; ++mt) {
#pragma unroll
        for (int r = 0; r < 4; ++r) {
            const int b = mt * 16 + grp * 4 + r;
            out[(size_t)b * V_ + v] = zr[mt][r] - lse_sh[b];
        }
    }
}

extern "C" void kernel_launch(void* const* d_in, const int* in_sizes, int n_in,
                              void* d_out, int out_size, void* d_ws, size_t ws_size,
                              hipStream_t stream) {
    const int* trainS = (const int*)d_in[0];
    const int* trainQ = (const int*)d_in[1];
    const float* trainVM = (const float*)d_in[2];
    const float* trainPM = (const float*)d_in[3];
    const float* trainQM = (const float*)d_in[5];
    const float* A1 = (const float*)d_in[6];
    const float* A2 = (const float*)d_in[7];
    const float* A3 = (const float*)d_in[8];
    const float* A4 = (const float*)d_in[9];
    const float* Wm = (const float*)d_in[10];
    const float* gamma = (const float*)d_in[12];
    const float* beta = (const float*)d_in[13];
    float* out = (float*)d_out;

    float* ws = (float*)d_ws;
    float* u_N = ws;                                 // B*E = 8192
    float* embA = ws + 8192;                         // 4*B*M*E = 3,276,800
    float* partial = embA + 4 * (B_ * M_ * E_);      // 256

    k_embed<<<B_ * M_, 256, 0, stream>>>(trainS, A1, A2, A3, A4, embA);
    k_hops<<<B_, 1024, 0, stream>>>(trainQ, trainQM, A1, embA, trainPM, u_N, partial);

    void* kargs[] = {(void*)&u_N, (void*)&Wm, (void*)&gamma, (void*)&beta,
                     (void*)&trainVM, (void*)&out, (void*)&partial};
    hipLaunchCooperativeKernel((void*)k_output, dim3(V_ / 64), dim3(256), kargs, 0, stream);
}

// Round 16
// 103.397 us; speedup vs baseline: 1.3143x; 1.3143x over previous
//
#include <hip/hip_runtime.h>
#include <math.h>

static constexpr int B_ = 32, M_ = 100, L_ = 30, LQ_ = 30, E_ = 256, V_ = 32000;

typedef __attribute__((ext_vector_type(8))) short bf16x8;
typedef __attribute__((ext_vector_type(4))) float f32x4;

__device__ __forceinline__ unsigned f2bf(float f) {   // RNE f32 -> bf16 bits
    unsigned u = __float_as_uint(f);
    return (u + 0x7FFFu + ((u >> 16) & 1u)) >> 16;
}

// ---------------- Kernel 1: story embeddings (fused 4 tables; ~66us line-fill wall:
// 393MB requested lines / ~6TB/s; invariant to ILP/occupancy/order/warmth).
__global__ __launch_bounds__(256) void k_embed(const int* __restrict__ trainS,
                                               const float* __restrict__ A1,
                                               const float* __restrict__ A2,
                                               const float* __restrict__ A3,
                                               const float* __restrict__ A4,
                                               float* __restrict__ embA) {
    const int bm = blockIdx.x;
    const int tbl = threadIdx.x >> 6;
    const int e0 = (threadIdx.x & 63) * 4;
    const float* __restrict__ A = (tbl == 0) ? A1 : (tbl == 1) ? A2 : (tbl == 2) ? A3 : A4;
    const float half_e = (E_ + 1) * 0.5f;
    const float half_j = (L_ + 1) * 0.5f;
    const float inv = 1.0f / (float)(E_ * L_);
    const float k0 = (float)(e0 + 1) - half_e;
    const float k1 = k0 + 1.f, k2 = k0 + 2.f, k3 = k0 + 3.f;

    int idx[L_];
#pragma unroll
    for (int l = 0; l < L_; ++l) idx[l] = trainS[bm * L_ + l];

    float4 acc = make_float4(0.f, 0.f, 0.f, 0.f);
#pragma unroll
    for (int c = 0; c < 2; ++c) {
        float4 r[15];
#pragma unroll
        for (int j = 0; j < 15; ++j)
            r[j] = *reinterpret_cast<const float4*>(A + (size_t)idx[c * 15 + j] * E_ + e0);
        __builtin_amdgcn_sched_barrier(0);
#pragma unroll
        for (int j = 0; j < 15; ++j) {
            const int l = c * 15 + j;
            const float coef = 4.0f * ((float)(l + 1) - half_j) * inv;
            acc.x += r[j].x * (1.0f + coef * k0);
            acc.y += r[j].y * (1.0f + coef * k1);
            acc.z += r[j].z * (1.0f + coef * k2);
            acc.w += r[j].w * (1.0f + coef * k3);
        }
    }
    *reinterpret_cast<float4*>(embA + (size_t)tbl * (B_ * M_ * E_) + (size_t)bm * E_ + e0) = acc;
}

// ---------------- Kernel 2: query embedding + three hops (R13 latency-restructured).
__global__ __launch_bounds__(1024) void k_hops(const int* __restrict__ trainQ,
                                               const float* __restrict__ trainQM,
                                               const float* __restrict__ A1,
                                               const float* __restrict__ embA,
                                               const float* __restrict__ trainPM,
                                               float* __restrict__ u_N,
                                               float* __restrict__ partial) {
    const int b = blockIdx.x;
    const int tid = threadIdx.x;
    const int lane = tid & 63;
    const int wave = tid >> 6;
    const int g = tid >> 8;
    const int e = tid & 255;
    if (tid < 8) partial[b * 8 + tid] = 0.f;
    __shared__ float u_sh[E_];
    __shared__ float sc[M_];
    __shared__ float p_sh[M_];
    __shared__ float osum[4][E_];

    {   // query embedding
        const float half_e = (E_ + 1) * 0.5f;
        const float half_j = (LQ_ + 1) * 0.5f;
        const float inv = 1.0f / (float)(E_ * LQ_);
        const float ke = (float)(e + 1) - half_e;
        const int l0 = g * 8;
        const int ln = (LQ_ - l0 < 8) ? (LQ_ - l0) : 8;
        int qi[8];
        float qm[8];
#pragma unroll
        for (int j = 0; j < 8; ++j) {
            if (j < ln) {
                qi[j] = trainQ[b * LQ_ + l0 + j];
                qm[j] = trainQM[b * LQ_ + l0 + j];
            } else { qi[j] = 0; qm[j] = 0.f; }
        }
        float r[8];
#pragma unroll
        for (int j = 0; j < 8; ++j)
            r[j] = (j < ln) ? A1[(size_t)qi[j] * E_ + e] : 0.f;
        float part = 0.f;
#pragma unroll
        for (int j = 0; j < 8; ++j) {
            const float pe = 1.0f + 4.0f * ke * ((float)(l0 + j + 1) - half_j) * inv;
            part += r[j] * pe * qm[j];
        }
        osum[g][e] = part;
    }
    __syncthreads();
    if (tid < E_) u_sh[tid] = osum[0][tid] + osum[1][tid] + osum[2][tid] + osum[3][tid];
    __syncthreads();

    for (int hop = 0; hop < 3; ++hop) {
        const float* memA = embA + (size_t)hop * (B_ * M_ * E_) + (size_t)b * M_ * E_;
        const float* memC = memA + (size_t)(B_ * M_ * E_);

        float rv[7][4];
#pragma unroll
        for (int t = 0; t < 7; ++t) {
            const int m = wave + t * 16;
            if (m < M_) {
                const float* row = memA + (size_t)m * E_;
#pragma unroll
                for (int j = 0; j < 4; ++j) rv[t][j] = row[lane + 64 * j];
            }
        }
        __builtin_amdgcn_sched_barrier(0);
#pragma unroll
        for (int t = 0; t < 7; ++t) {
            const int m = wave + t * 16;
            if (m < M_) {
                float part = rv[t][0] * u_sh[lane] + rv[t][1] * u_sh[lane + 64]
                           + rv[t][2] * u_sh[lane + 128] + rv[t][3] * u_sh[lane + 192];
#pragma unroll
                for (int off = 32; off > 0; off >>= 1)
                    part += __shfl_xor(part, off, 64);
                if (lane == 0) sc[m] = part * trainPM[b * M_ + m];
            }
        }

        float cv[25];
        {
            const float* crow = memC + e;
            const int m0 = g * 25;
#pragma unroll
            for (int mm = 0; mm < 25; ++mm)
                cv[mm] = crow[(size_t)(m0 + mm) * E_];
        }
        __builtin_amdgcn_sched_barrier(0);
        __syncthreads();

        if (wave == 0) {
            const float pm0 = (lane < M_) ? trainPM[b * M_ + lane] : 0.f;
            const float pm1 = (lane + 64 < M_) ? trainPM[b * M_ + lane + 64] : 0.f;
            const float x0 = (lane < M_ && pm0 > 0.f) ? sc[lane] : -1e30f;
            const float x1 = (lane + 64 < M_ && pm1 > 0.f) ? sc[lane + 64] : -1e30f;
            float mx = fmaxf(x0, x1);
#pragma unroll
            for (int off = 32; off > 0; off >>= 1)
                mx = fmaxf(mx, __shfl_xor(mx, off, 64));
            const float e0v = (lane < M_) ? expf(x0 - mx) * pm0 : 0.f;
            const float e1v = (lane + 64 < M_) ? expf(x1 - mx) * pm1 : 0.f;
            float ssum = e0v + e1v;
#pragma unroll
            for (int off = 32; off > 0; off >>= 1)
                ssum += __shfl_xor(ssum, off, 64);
            const float invs = 1.0f / (ssum + 1e-13f);
            if (lane < M_) p_sh[lane] = e0v * invs;
            if (lane + 64 < M_) p_sh[lane + 64] = e1v * invs;
        }
        __syncthreads();

        {
            float acc = 0.f;
            const int m0 = g * 25;
#pragma unroll
            for (int mm = 0; mm < 25; ++mm)
                acc += p_sh[m0 + mm] * cv[mm];
            osum[g][e] = acc;
        }
        __syncthreads();
        if (tid < E_) u_sh[tid] += osum[0][tid] + osum[1][tid] + osum[2][tid] + osum[3][tid];
        __syncthreads();
    }
    if (tid < E_) u_N[b * E_ + tid] = u_sh[tid];
}

// ---------------- Kernel 3: MFMA GEMM + batch-LN + log(VM) + shfl-reduced exp-partials.
// R9 structure, epilogue de-atomized (4 shfl rounds -> 32 atomics/wave instead of 512).
__global__ __launch_bounds__(256) void k_output(const float* __restrict__ u_N,
                                                const float* __restrict__ Wm,
                                                const float* __restrict__ gamma,
                                                const float* __restrict__ beta,
                                                const float* __restrict__ VM,
                                                float* __restrict__ z,
                                                float* __restrict__ partial) {
    __shared__ char uAraw[32 * 512];   // bf16 u[m][k], swizzled 16B granules
    __shared__ float pex[B_];
    const int tid = threadIdx.x;
    {
        const int m = tid >> 3;
        const int kc = (tid & 7) * 32;
        const float4* src = reinterpret_cast<const float4*>(u_N + m * E_ + kc);
#pragma unroll
        for (int j = 0; j < 4; ++j) {
            const float4 f0 = src[2 * j];
            const float4 f1 = src[2 * j + 1];
            uint4 q;
            q.x = f2bf(f0.x) | (f2bf(f0.y) << 16);
            q.y = f2bf(f0.z) | (f2bf(f0.w) << 16);
            q.z = f2bf(f1.x) | (f2bf(f1.y) << 16);
            q.w = f2bf(f1.z) | (f2bf(f1.w) << 16);
            const int k16 = kc / 8 + j;
            const int off = m * 512 + ((k16 * 16) ^ ((m & 7) << 4));
            *reinterpret_cast<uint4*>(uAraw + off) = q;
        }
    }
    if (tid < B_) pex[tid] = 0.f;
    __syncthreads();

    const int lane = tid & 63;
    const int wv = tid >> 6;
    const int col = lane & 15;
    const int grp = lane >> 4;
    const int n0 = (blockIdx.x * 4 + wv) * 16;
    const int v = n0 + col;

    float4 wreg[16];
    {
        const float* wrow = Wm + (size_t)v * E_ + grp * 8;
#pragma unroll
        for (int s = 0; s < 8; ++s) {
            wreg[2 * s] = *reinterpret_cast<const float4*>(wrow + s * 32);
            wreg[2 * s + 1] = *reinterpret_cast<const float4*>(wrow + s * 32 + 4);
        }
    }
    __builtin_amdgcn_sched_barrier(0);

    bf16x8 af[2][8];
#pragma unroll
    for (int mt = 0; mt < 2; ++mt) {
        const int m = mt * 16 + col;
#pragma unroll
        for (int s = 0; s < 8; ++s) {
            const int k16 = s * 4 + grp;
            const int off = m * 512 + ((k16 * 16) ^ ((m & 7) << 4));
            af[mt][s] = *reinterpret_cast<bf16x8*>(uAraw + off);
        }
    }

    f32x4 acc0 = {0.f, 0.f, 0.f, 0.f};
    f32x4 acc1 = {0.f, 0.f, 0.f, 0.f};
#pragma unroll
    for (int s = 0; s < 8; ++s) {
        const float4 w0 = wreg[2 * s], w1 = wreg[2 * s + 1];
        bf16x8 bf;
        bf[0] = (short)f2bf(w0.x); bf[1] = (short)f2bf(w0.y);
        bf[2] = (short)f2bf(w0.z); bf[3] = (short)f2bf(w0.w);
        bf[4] = (short)f2bf(w1.x); bf[5] = (short)f2bf(w1.y);
        bf[6] = (short)f2bf(w1.z); bf[7] = (short)f2bf(w1.w);
        acc0 = __builtin_amdgcn_mfma_f32_16x16x32_bf16(af[0][s], bf, acc0, 0, 0, 0);
        acc1 = __builtin_amdgcn_mfma_f32_16x16x32_bf16(af[1][s], bf, acc1, 0, 0, 0);
    }

    float s1 = 0.f, s2 = 0.f;
#pragma unroll
    for (int r = 0; r < 4; ++r) {
        s1 += acc0[r] + acc1[r];
        s2 += acc0[r] * acc0[r] + acc1[r] * acc1[r];
    }
    s1 += __shfl_xor(s1, 16, 64);
    s2 += __shfl_xor(s2, 16, 64);
    s1 += __shfl_xor(s1, 32, 64);
    s2 += __shfl_xor(s2, 32, 64);
    const float mean = s1 * (1.0f / B_);
    const float var = s2 * (1.0f / B_) - mean * mean;
    const float rstd = rsqrtf(var + 1e-5f);
    const float gg = gamma[v], be = beta[v];

    // z writes + exp partials, shfl-reduced across the 16 cols (b = mt*16 + grp*4 + r).
    float ex[2][4];
#pragma unroll
    for (int mt = 0; mt < 2; ++mt) {
#pragma unroll
        for (int r = 0; r < 4; ++r) {
            const int b = mt * 16 + grp * 4 + r;
            const float wx = (mt == 0) ? acc0[r] : acc1[r];
            const float y = gg * (wx - mean) * rstd + be;
            const size_t row = (size_t)b * V_ + v;
            const float vm = VM[row] + 1e-13f;
            z[row] = y + logf(vm);
            ex[mt][r] = vm * expf(y);
        }
    }
#pragma unroll
    for (int off = 1; off < 16; off <<= 1) {
#pragma unroll
        for (int mt = 0; mt < 2; ++mt)
#pragma unroll
            for (int r = 0; r < 4; ++r)
                ex[mt][r] += __shfl_xor(ex[mt][r], off, 64);
    }
    if (col == 0) {
#pragma unroll
        for (int mt = 0; mt < 2; ++mt)
#pragma unroll
            for (int r = 0; r < 4; ++r)
                atomicAdd(&pex[mt * 16 + grp * 4 + r], ex[mt][r]);
    }
    __syncthreads();
    if (tid < B_) atomicAdd(&partial[tid * 8 + (blockIdx.x & 7)], pex[tid]);
}

// ---------------- Kernel 4: out = z - log(sum_s partial[b][s])
__global__ __launch_bounds__(256) void k_final(const float* __restrict__ z,
                                               const float* __restrict__ partial,
                                               float* __restrict__ out) {
    const int idx = blockIdx.x * 256 + threadIdx.x;
    const int b = idx / (V_ / 4);
    const int v4 = idx % (V_ / 4);
    float s = 0.f;
#pragma unroll
    for (int k = 0; k < 8; ++k) s += partial[b * 8 + k];
    const float lse = logf(s);
    const float4 x = reinterpret_cast<const float4*>(z + (size_t)b * V_)[v4];
    float4 o;
    o.x = x.x - lse; o.y = x.y - lse; o.z = x.z - lse; o.w = x.w - lse;
    reinterpret_cast<float4*>(out + (size_t)b * V_)[v4] = o;
}

extern "C" void kernel_launch(void* const* d_in, const int* in_sizes, int n_in,
                              void* d_out, int out_size, void* d_ws, size_t ws_size,
                              hipStream_t stream) {
    const int* trainS = (const int*)d_in[0];
    const int* trainQ = (const int*)d_in[1];
    const float* trainVM = (const float*)d_in[2];
    const float* trainPM = (const float*)d_in[3];
    const float* trainQM = (const float*)d_in[5];
    const float* A1 = (const float*)d_in[6];
    const float* A2 = (const float*)d_in[7];
    const float* A3 = (const float*)d_in[8];
    const float* A4 = (const float*)d_in[9];
    const float* Wm = (const float*)d_in[10];
    const float* gamma = (const float*)d_in[12];
    const float* beta = (const float*)d_in[13];
    float* out = (float*)d_out;

    float* ws = (float*)d_ws;
    float* u_N = ws;                                 // B*E = 8192
    float* embA = ws + 8192;                         // 4*B*M*E = 3,276,800
    float* z = embA + 4 * (B_ * M_ * E_);            // B*V = 1,024,000
    float* partial = z + (size_t)B_ * V_;            // 256

    k_embed<<<B_ * M_, 256, 0, stream>>>(trainS, A1, A2, A3, A4, embA);
    k_hops<<<B_, 1024, 0, stream>>>(trainQ, trainQM, A1, embA, trainPM, u_N, partial);
    k_output<<<V_ / 64, 256, 0, stream>>>(u_N, Wm, gamma, beta, trainVM, z, partial);
    k_final<<<(B_ * V_ / 4) / 256, 256, 0, stream>>>(z, partial, out);
}

// Round 17
// 102.341 us; speedup vs baseline: 1.3279x; 1.0103x over previous
//
#include <hip/hip_runtime.h>
#include <math.h>

static constexpr int B_ = 32, M_ = 100, L_ = 30, LQ_ = 30, E_ = 256, V_ = 32000;

typedef __attribute__((ext_vector_type(8))) short bf16x8;
typedef __attribute__((ext_vector_type(4))) float f32x4;

__device__ __forceinline__ unsigned f2bf(float f) {   // RNE f32 -> bf16 bits
    unsigned u = __float_as_uint(f);
    return (u + 0x7FFFu + ((u >> 16) & 1u)) >> 16;
}

// ---------------- Kernel 1: story embeddings (fused 4 tables; ~66us line-fill wall:
// 393MB requested lines / ~6TB/s; invariant to ILP/occupancy/order/warmth).
__global__ __launch_bounds__(256) void k_embed(const int* __restrict__ trainS,
                                               const float* __restrict__ A1,
                                               const float* __restrict__ A2,
                                               const float* __restrict__ A3,
                                               const float* __restrict__ A4,
                                               float* __restrict__ embA) {
    const int bm = blockIdx.x;
    const int tbl = threadIdx.x >> 6;
    const int e0 = (threadIdx.x & 63) * 4;
    const float* __restrict__ A = (tbl == 0) ? A1 : (tbl == 1) ? A2 : (tbl == 2) ? A3 : A4;
    const float half_e = (E_ + 1) * 0.5f;
    const float half_j = (L_ + 1) * 0.5f;
    const float inv = 1.0f / (float)(E_ * L_);
    const float k0 = (float)(e0 + 1) - half_e;
    const float k1 = k0 + 1.f, k2 = k0 + 2.f, k3 = k0 + 3.f;

    int idx[L_];
#pragma unroll
    for (int l = 0; l < L_; ++l) idx[l] = trainS[bm * L_ + l];

    float4 acc = make_float4(0.f, 0.f, 0.f, 0.f);
#pragma unroll
    for (int c = 0; c < 2; ++c) {
        float4 r[15];
#pragma unroll
        for (int j = 0; j < 15; ++j)
            r[j] = *reinterpret_cast<const float4*>(A + (size_t)idx[c * 15 + j] * E_ + e0);
        __builtin_amdgcn_sched_barrier(0);
#pragma unroll
        for (int j = 0; j < 15; ++j) {
            const int l = c * 15 + j;
            const float coef = 4.0f * ((float)(l + 1) - half_j) * inv;
            acc.x += r[j].x * (1.0f + coef * k0);
            acc.y += r[j].y * (1.0f + coef * k1);
            acc.z += r[j].z * (1.0f + coef * k2);
            acc.w += r[j].w * (1.0f + coef * k3);
        }
    }
    *reinterpret_cast<float4*>(embA + (size_t)tbl * (B_ * M_ * E_) + (size_t)bm * E_ + e0) = acc;
}

// ---------------- Kernel 2: query embedding + three hops (R13 latency-restructured).
__global__ __launch_bounds__(1024) void k_hops(const int* __restrict__ trainQ,
                                               const float* __restrict__ trainQM,
                                               const float* __restrict__ A1,
                                               const float* __restrict__ embA,
                                               const float* __restrict__ trainPM,
                                               float* __restrict__ u_N,
                                               float* __restrict__ partial) {
    const int b = blockIdx.x;
    const int tid = threadIdx.x;
    const int lane = tid & 63;
    const int wave = tid >> 6;
    const int g = tid >> 8;
    const int e = tid & 255;
    if (tid < 8) partial[b * 8 + tid] = 0.f;
    __shared__ float u_sh[E_];
    __shared__ float sc[M_];
    __shared__ float p_sh[M_];
    __shared__ float osum[4][E_];

    {   // query embedding
        const float half_e = (E_ + 1) * 0.5f;
        const float half_j = (LQ_ + 1) * 0.5f;
        const float inv = 1.0f / (float)(E_ * LQ_);
        const float ke = (float)(e + 1) - half_e;
        const int l0 = g * 8;
        const int ln = (LQ_ - l0 < 8) ? (LQ_ - l0) : 8;
        int qi[8];
        float qm[8];
#pragma unroll
        for (int j = 0; j < 8; ++j) {
            if (j < ln) {
                qi[j] = trainQ[b * LQ_ + l0 + j];
                qm[j] = trainQM[b * LQ_ + l0 + j];
            } else { qi[j] = 0; qm[j] = 0.f; }
        }
        float r[8];
#pragma unroll
        for (int j = 0; j < 8; ++j)
            r[j] = (j < ln) ? A1[(size_t)qi[j] * E_ + e] : 0.f;
        float part = 0.f;
#pragma unroll
        for (int j = 0; j < 8; ++j) {
            const float pe = 1.0f + 4.0f * ke * ((float)(l0 + j + 1) - half_j) * inv;
            part += r[j] * pe * qm[j];
        }
        osum[g][e] = part;
    }
    __syncthreads();
    if (tid < E_) u_sh[tid] = osum[0][tid] + osum[1][tid] + osum[2][tid] + osum[3][tid];
    __syncthreads();

    for (int hop = 0; hop < 3; ++hop) {
        const float* memA = embA + (size_t)hop * (B_ * M_ * E_) + (size_t)b * M_ * E_;
        const float* memC = memA + (size_t)(B_ * M_ * E_);

        float rv[7][4];
#pragma unroll
        for (int t = 0; t < 7; ++t) {
            const int m = wave + t * 16;
            if (m < M_) {
                const float* row = memA + (size_t)m * E_;
#pragma unroll
                for (int j = 0; j < 4; ++j) rv[t][j] = row[lane + 64 * j];
            }
        }
        __builtin_amdgcn_sched_barrier(0);
#pragma unroll
        for (int t = 0; t < 7; ++t) {
            const int m = wave + t * 16;
            if (m < M_) {
                float part = rv[t][0] * u_sh[lane] + rv[t][1] * u_sh[lane + 64]
                           + rv[t][2] * u_sh[lane + 128] + rv[t][3] * u_sh[lane + 192];
#pragma unroll
                for (int off = 32; off > 0; off >>= 1)
                    part += __shfl_xor(part, off, 64);
                if (lane == 0) sc[m] = part * trainPM[b * M_ + m];
            }
        }

        float cv[25];
        {
            const float* crow = memC + e;
            const int m0 = g * 25;
#pragma unroll
            for (int mm = 0; mm < 25; ++mm)
                cv[mm] = crow[(size_t)(m0 + mm) * E_];
        }
        __builtin_amdgcn_sched_barrier(0);
        __syncthreads();

        if (wave == 0) {
            const float pm0 = (lane < M_) ? trainPM[b * M_ + lane] : 0.f;
            const float pm1 = (lane + 64 < M_) ? trainPM[b * M_ + lane + 64] : 0.f;
            const float x0 = (lane < M_ && pm0 > 0.f) ? sc[lane] : -1e30f;
            const float x1 = (lane + 64 < M_ && pm1 > 0.f) ? sc[lane + 64] : -1e30f;
            float mx = fmaxf(x0, x1);
#pragma unroll
            for (int off = 32; off > 0; off >>= 1)
                mx = fmaxf(mx, __shfl_xor(mx, off, 64));
            const float e0v = (lane < M_) ? expf(x0 - mx) * pm0 : 0.f;
            const float e1v = (lane + 64 < M_) ? expf(x1 - mx) * pm1 : 0.f;
            float ssum = e0v + e1v;
#pragma unroll
            for (int off = 32; off > 0; off >>= 1)
                ssum += __shfl_xor(ssum, off, 64);
            const float invs = 1.0f / (ssum + 1e-13f);
            if (lane < M_) p_sh[lane] = e0v * invs;
            if (lane + 64 < M_) p_sh[lane + 64] = e1v * invs;
        }
        __syncthreads();

        {
            float acc = 0.f;
            const int m0 = g * 25;
#pragma unroll
            for (int mm = 0; mm < 25; ++mm)
                acc += p_sh[m0 + mm] * cv[mm];
            osum[g][e] = acc;
        }
        __syncthreads();
        if (tid < E_) u_sh[tid] += osum[0][tid] + osum[1][tid] + osum[2][tid] + osum[3][tid];
        __syncthreads();
    }
    if (tid < E_) u_N[b * E_ + tid] = u_sh[tid];
}

// ---------------- Kernel 3: MFMA GEMM + batch-LN + log(VM) + shfl-reduced exp-partials.
// R15 + latency hoist: VM/gamma/beta loads issued BEFORE the MFMA chain (addresses
// independent of results) so their ~600cy latency hides under the 16 MFMAs.
__global__ __launch_bounds__(256) void k_output(const float* __restrict__ u_N,
                                                const float* __restrict__ Wm,
                                                const float* __restrict__ gamma,
                                                const float* __restrict__ beta,
                                                const float* __restrict__ VM,
                                                float* __restrict__ z,
                                                float* __restrict__ partial) {
    __shared__ char uAraw[32 * 512];   // bf16 u[m][k], swizzled 16B granules
    __shared__ float pex[B_];
    const int tid = threadIdx.x;
    {
        const int m = tid >> 3;
        const int kc = (tid & 7) * 32;
        const float4* src = reinterpret_cast<const float4*>(u_N + m * E_ + kc);
#pragma unroll
        for (int j = 0; j < 4; ++j) {
            const float4 f0 = src[2 * j];
            const float4 f1 = src[2 * j + 1];
            uint4 q;
            q.x = f2bf(f0.x) | (f2bf(f0.y) << 16);
            q.y = f2bf(f0.z) | (f2bf(f0.w) << 16);
            q.z = f2bf(f1.x) | (f2bf(f1.y) << 16);
            q.w = f2bf(f1.z) | (f2bf(f1.w) << 16);
            const int k16 = kc / 8 + j;
            const int off = m * 512 + ((k16 * 16) ^ ((m & 7) << 4));
            *reinterpret_cast<uint4*>(uAraw + off) = q;
        }
    }
    if (tid < B_) pex[tid] = 0.f;
    __syncthreads();

    const int lane = tid & 63;
    const int wv = tid >> 6;
    const int col = lane & 15;
    const int grp = lane >> 4;
    const int n0 = (blockIdx.x * 4 + wv) * 16;
    const int v = n0 + col;

    // ---- W fragments (16 float4) issued first
    float4 wreg[16];
    {
        const float* wrow = Wm + (size_t)v * E_ + grp * 8;
#pragma unroll
        for (int s = 0; s < 8; ++s) {
            wreg[2 * s] = *reinterpret_cast<const float4*>(wrow + s * 32);
            wreg[2 * s + 1] = *reinterpret_cast<const float4*>(wrow + s * 32 + 4);
        }
    }
    // ---- hoist epilogue operands: VM (8 scattered), gamma, beta — independent of MFMA
    float vmv[2][4];
#pragma unroll
    for (int mt = 0; mt < 2; ++mt)
#pragma unroll
        for (int r = 0; r < 4; ++r) {
            const int b = mt * 16 + grp * 4 + r;
            vmv[mt][r] = VM[(size_t)b * V_ + v];
        }
    const float gg = gamma[v], be = beta[v];
    __builtin_amdgcn_sched_barrier(0);

    bf16x8 af[2][8];
#pragma unroll
    for (int mt = 0; mt < 2; ++mt) {
        const int m = mt * 16 + col;
#pragma unroll
        for (int s = 0; s < 8; ++s) {
            const int k16 = s * 4 + grp;
            const int off = m * 512 + ((k16 * 16) ^ ((m & 7) << 4));
            af[mt][s] = *reinterpret_cast<bf16x8*>(uAraw + off);
        }
    }

    f32x4 acc0 = {0.f, 0.f, 0.f, 0.f};
    f32x4 acc1 = {0.f, 0.f, 0.f, 0.f};
#pragma unroll
    for (int s = 0; s < 8; ++s) {
        const float4 w0 = wreg[2 * s], w1 = wreg[2 * s + 1];
        bf16x8 bf;
        bf[0] = (short)f2bf(w0.x); bf[1] = (short)f2bf(w0.y);
        bf[2] = (short)f2bf(w0.z); bf[3] = (short)f2bf(w0.w);
        bf[4] = (short)f2bf(w1.x); bf[5] = (short)f2bf(w1.y);
        bf[6] = (short)f2bf(w1.z); bf[7] = (short)f2bf(w1.w);
        acc0 = __builtin_amdgcn_mfma_f32_16x16x32_bf16(af[0][s], bf, acc0, 0, 0, 0);
        acc1 = __builtin_amdgcn_mfma_f32_16x16x32_bf16(af[1][s], bf, acc1, 0, 0, 0);
    }

    float s1 = 0.f, s2 = 0.f;
#pragma unroll
    for (int r = 0; r < 4; ++r) {
        s1 += acc0[r] + acc1[r];
        s2 += acc0[r] * acc0[r] + acc1[r] * acc1[r];
    }
    s1 += __shfl_xor(s1, 16, 64);
    s2 += __shfl_xor(s2, 16, 64);
    s1 += __shfl_xor(s1, 32, 64);
    s2 += __shfl_xor(s2, 32, 64);
    const float mean = s1 * (1.0f / B_);
    const float var = s2 * (1.0f / B_) - mean * mean;
    const float rstd = rsqrtf(var + 1e-5f);

    // z writes + exp partials, shfl-reduced across the 16 cols (b = mt*16 + grp*4 + r).
    float ex[2][4];
#pragma unroll
    for (int mt = 0; mt < 2; ++mt) {
#pragma unroll
        for (int r = 0; r < 4; ++r) {
            const int b = mt * 16 + grp * 4 + r;
            const float wx = (mt == 0) ? acc0[r] : acc1[r];
            const float y = gg * (wx - mean) * rstd + be;
            const float vm = vmv[mt][r] + 1e-13f;
            z[(size_t)b * V_ + v] = y + logf(vm);
            ex[mt][r] = vm * expf(y);
        }
    }
#pragma unroll
    for (int off = 1; off < 16; off <<= 1) {
#pragma unroll
        for (int mt = 0; mt < 2; ++mt)
#pragma unroll
            for (int r = 0; r < 4; ++r)
                ex[mt][r] += __shfl_xor(ex[mt][r], off, 64);
    }
    if (col == 0) {
#pragma unroll
        for (int mt = 0; mt < 2; ++mt)
#pragma unroll
            for (int r = 0; r < 4; ++r)
                atomicAdd(&pex[mt * 16 + grp * 4 + r], ex[mt][r]);
    }
    __syncthreads();
    if (tid < B_) atomicAdd(&partial[tid * 8 + (blockIdx.x & 7)], pex[tid]);
}

// ---------------- Kernel 4: out = z - log(sum_s partial[b][s])
__global__ __launch_bounds__(256) void k_final(const float* __restrict__ z,
                                               const float* __restrict__ partial,
                                               float* __restrict__ out) {
    const int idx = blockIdx.x * 256 + threadIdx.x;
    const int b = idx / (V_ / 4);
    const int v4 = idx % (V_ / 4);
    float s = 0.f;
#pragma unroll
    for (int k = 0; k < 8; ++k) s += partial[b * 8 + k];
    const float lse = logf(s);
    const float4 x = reinterpret_cast<const float4*>(z + (size_t)b * V_)[v4];
    float4 o;
    o.x = x.x - lse; o.y = x.y - lse; o.z = x.z - lse; o.w = x.w - lse;
    reinterpret_cast<float4*>(out + (size_t)b * V_)[v4] = o;
}

extern "C" void kernel_launch(void* const* d_in, const int* in_sizes, int n_in,
                              void* d_out, int out_size, void* d_ws, size_t ws_size,
                              hipStream_t stream) {
    const int* trainS = (const int*)d_in[0];
    const int* trainQ = (const int*)d_in[1];
    const float* trainVM = (const float*)d_in[2];
    const float* trainPM = (const float*)d_in[3];
    const float* trainQM = (const float*)d_in[5];
    const float* A1 = (const float*)d_in[6];
    const float* A2 = (const float*)d_in[7];
    const float* A3 = (const float*)d_in[8];
    const float* A4 = (const float*)d_in[9];
    const float* Wm = (const float*)d_in[10];
    const float* gamma = (const float*)d_in[12];
    const float* beta = (const float*)d_in[13];
    float* out = (float*)d_out;

    float* ws = (float*)d_ws;
    float* u_N = ws;                                 // B*E = 8192
    float* embA = ws + 8192;                         // 4*B*M*E = 3,276,800
    float* z = embA + 4 * (B_ * M_ * E_);            // B*V = 1,024,000
    float* partial = z + (size_t)B_ * V_;            // 256

    k_embed<<<B_ * M_, 256, 0, stream>>>(trainS, A1, A2, A3, A4, embA);
    k_hops<<<B_, 1024, 0, stream>>>(trainQ, trainQM, A1, embA, trainPM, u_N, partial);
    k_output<<<V_ / 64, 256, 0, stream>>>(u_N, Wm, gamma, beta, trainVM, z, partial);
    k_final<<<(B_ * V_ / 4) / 256, 256, 0, stream>>>(z, partial, out);
}